// Round 4
// baseline (137.984 us; speedup 1.0000x reference)
//
#include <hip/hip_runtime.h>

#define GS 7
#define CC 30           // 5*NB + NC

// Per-cell YOLO v1 losses. f/t must be indexable with compile-time-constant
// offsets only (callers pass registers via SROA'd local arrays, or global
// pointers for the scalar tail path).
__device__ __forceinline__ void cell_losses(const float* __restrict__ f,
                                            const float* __restrict__ t,
                                            float& o_boxes, float& o_conf, float& o_cls) {
    const float inv_gs = 0.14285714285714285f;   // 1/7; mul instead of div (abs err ~1e-7 vs 0.4 threshold)

    const float conf_t = t[4];
    const float coord  = (conf_t > 0.0f)  ? 1.0f : 0.0f;
    const float noobj  = (conf_t == 0.0f) ? 1.0f : 0.0f;

    // no-object confidence loss (both predicted boxes)
    const float d0 = f[4] - t[4];
    const float d1 = f[9] - t[9];
    const float l_noobj = noobj * (d0 * d0 + d1 * d1);

    // target box corners (box 0 of targets)
    const float bt0 = t[0], bt1 = t[1], bt2 = t[2], bt3 = t[3];
    const float ttx = bt0 * inv_gs, tty = bt1 * inv_gs;
    const float txmin = ttx - 0.5f * bt2, tymin = tty - 0.5f * bt3;
    const float txmax = ttx + 0.5f * bt2, tymax = tty + 0.5f * bt3;
    const float tarea = (txmax - txmin) * (tymax - tymin);

    // predicted boxes
    const float px0 = f[0], py0 = f[1], pw0 = f[2], ph0 = f[3], pc0 = f[4];
    const float px1 = f[5], py1 = f[6], pw1 = f[7], ph1 = f[8], pc1 = f[9];

    float iou0, iou1;
    {
        const float cx = px0 * inv_gs, cy = py0 * inv_gs;
        const float xmin = cx - 0.5f * pw0, ymin = cy - 0.5f * ph0;
        const float xmax = cx + 0.5f * pw0, ymax = cy + 0.5f * ph0;
        const float wx = fmaxf(fminf(xmax, txmax) - fmaxf(xmin, txmin), 0.0f);
        const float wy = fmaxf(fminf(ymax, tymax) - fmaxf(ymin, tymin), 0.0f);
        const float inter = wx * wy;
        const float parea = (xmax - xmin) * (ymax - ymin);
        iou0 = inter / (parea + tarea - inter);
    }
    {
        const float cx = px1 * inv_gs, cy = py1 * inv_gs;
        const float xmin = cx - 0.5f * pw1, ymin = cy - 0.5f * ph1;
        const float xmax = cx + 0.5f * pw1, ymax = cy + 0.5f * ph1;
        const float wx = fmaxf(fminf(xmax, txmax) - fmaxf(xmin, txmin), 0.0f);
        const float wy = fmaxf(fminf(ymax, tymax) - fmaxf(ymin, tymin), 0.0f);
        const float inter = wx * wy;
        const float parea = (xmax - xmin) * (ymax - ymin);
        iou1 = inter / (parea + tarea - inter);
    }
    // jnp.argmax picks first max on ties -> strict > for box 1
    const bool  sel1    = iou1 > iou0;
    const float max_iou = fmaxf(iou0, iou1);

    const float rp0 = sel1 ? px1 : px0;
    const float rp1 = sel1 ? py1 : py0;
    const float rp2 = sel1 ? pw1 : pw0;
    const float rp3 = sel1 ? ph1 : ph0;
    const float rp4 = sel1 ? pc1 : pc0;

    const float dx = rp0 - bt0, dy = rp1 - bt1;
    const float sw = sqrtf(rp2) - sqrtf(bt2);
    const float sh = sqrtf(rp3) - sqrtf(bt3);
    const float dob = rp4 - max_iou;
    const float l_box = dx * dx + dy * dy + sw * sw + sh * sh;
    const float l_obj = dob * dob;

    float l_cls = 0.0f;
    #pragma unroll
    for (int j = 10; j < 30; ++j) {
        const float d = f[j] - t[j];
        l_cls += d * d;
    }

    o_boxes += coord * l_box;
    o_conf  += coord * l_obj + 0.5f * l_noobj;
    o_cls   += coord * l_cls;
}

// ---------------- main: one thread per CELL PAIR (240 B = 15 float4) ----------------
__global__ __launch_bounds__(256) void yolo_main(
        const float* __restrict__ in,
        const float* __restrict__ tg,
        float* __restrict__ ws,
        int npairs, int ncells, int pstride) {
    const int pair = blockIdx.x * 256 + threadIdx.x;

    float a_boxes = 0.0f, a_conf = 0.0f, a_class = 0.0f;

    if (pair < npairs) {
        const float4* gin = (const float4*)(in + (size_t)pair * (2 * CC));
        const float4* gtg = (const float4*)(tg + (size_t)pair * (2 * CC));

        float fi[60], ft[60];
        float4* vi = (float4*)fi;
        float4* vt = (float4*)ft;
        // All 30 16B loads issued as one independent batch -> 480 B/lane in flight.
        #pragma unroll
        for (int k = 0; k < 15; ++k) vi[k] = gin[k];
        #pragma unroll
        for (int k = 0; k < 15; ++k) vt[k] = gtg[k];

        cell_losses(fi,      ft,      a_boxes, a_conf, a_class);   // cell A
        cell_losses(fi + 30, ft + 30, a_boxes, a_conf, a_class);   // cell B
    }
    // odd-ncells tail: one thread handles the last cell via (scalar) global loads
    if ((ncells & 1) && pair == npairs) {
        const size_t c = (size_t)(ncells - 1) * CC;
        cell_losses(in + c, tg + c, a_boxes, a_conf, a_class);
    }

    // wave-64 shuffle reduce
    #pragma unroll
    for (int off = 32; off > 0; off >>= 1) {
        a_boxes += __shfl_down(a_boxes, off, 64);
        a_conf  += __shfl_down(a_conf,  off, 64);
        a_class += __shfl_down(a_class, off, 64);
    }
    __shared__ float s_red[4][3];
    const int wave = threadIdx.x >> 6;
    if ((threadIdx.x & 63) == 0) {
        s_red[wave][0] = a_boxes;
        s_red[wave][1] = a_conf;
        s_red[wave][2] = a_class;
    }
    __syncthreads();
    if (threadIdx.x == 0) {
        const float b = s_red[0][0] + s_red[1][0] + s_red[2][0] + s_red[3][0];
        const float c = s_red[0][1] + s_red[1][1] + s_red[2][1] + s_red[3][1];
        const float k = s_red[0][2] + s_red[1][2] + s_red[2][2] + s_red[3][2];
        // non-atomic block partials -> no same-address contention
        ws[blockIdx.x]               = b;
        ws[blockIdx.x + pstride]     = c;
        ws[blockIdx.x + 2 * pstride] = k;
    }
}

// ---------------- finalize: sum block partials, scale, write out ----------------
__global__ __launch_bounds__(256) void yolo_finalize(
        const float* __restrict__ ws, float* __restrict__ out,
        int nblocks, int pstride, float inv_bs) {
    float b = 0.0f, c = 0.0f, k = 0.0f;
    for (int i = threadIdx.x; i < nblocks; i += 256) {
        b += ws[i];
        c += ws[i + pstride];
        k += ws[i + 2 * pstride];
    }
    #pragma unroll
    for (int off = 32; off > 0; off >>= 1) {
        b += __shfl_down(b, off, 64);
        c += __shfl_down(c, off, 64);
        k += __shfl_down(k, off, 64);
    }
    __shared__ float s_red[4][3];
    const int wave = threadIdx.x >> 6;
    if ((threadIdx.x & 63) == 0) {
        s_red[wave][0] = b;
        s_red[wave][1] = c;
        s_red[wave][2] = k;
    }
    __syncthreads();
    if (threadIdx.x == 0) {
        const float tb = s_red[0][0] + s_red[1][0] + s_red[2][0] + s_red[3][0];
        const float tc = s_red[0][1] + s_red[1][1] + s_red[2][1] + s_red[3][1];
        const float tk = s_red[0][2] + s_red[1][2] + s_red[2][2] + s_red[3][2];
        out[0] = 0.5f * tb * inv_bs;   // LAMBDA_COORD*(xy+wh)/bs
        out[1] = tc * inv_bs;          // (obj + 0.5*noobj)/bs
        out[2] = tk * inv_bs;          // class/bs
    }
}

extern "C" void kernel_launch(void* const* d_in, const int* in_sizes, int n_in,
                              void* d_out, int out_size, void* d_ws, size_t ws_size,
                              hipStream_t stream) {
    const float* in = (const float*)d_in[0];
    const float* tg = (const float*)d_in[1];
    float* out = (float*)d_out;
    float* ws  = (float*)d_ws;

    const int ncells = in_sizes[0] / CC;          // B * 49
    const int B = ncells / (GS * GS);
    const float inv_bs = 1.0f / (float)B;

    const int npairs  = ncells / 2;               // 200704 at B=8192
    const int nblocks = (npairs + 255) / 256;     // 784 exactly at B=8192
    const int pstride = nblocks;

    yolo_main<<<nblocks, 256, 0, stream>>>(in, tg, ws, npairs, ncells, pstride);
    yolo_finalize<<<1, 256, 0, stream>>>(ws, out, nblocks, pstride, inv_bs);
}

// Round 5
// 117.527 us; speedup vs baseline: 1.1741x; 1.1741x over previous
//
#include <hip/hip_runtime.h>

#define GS 7
#define CC 30              // 5*NB + NC
#define CPB 256            // cells per block

// ---------------- main: coalesced float4 -> LDS staging, per-cell compute ----------------
__global__ __launch_bounds__(256) void yolo_main(
        const float* __restrict__ in,
        const float* __restrict__ tg,
        float* __restrict__ ws,
        int ncells, int pstride) {
    __shared__ float s_in[CPB * CC];   // 30720 B
    __shared__ float s_tg[CPB * CC];   // 30720 B
    __shared__ float s_red[4][3];

    const int tid  = threadIdx.x;
    const int base = blockIdx.x * CPB;
    int n = ncells - base;
    if (n > CPB) n = CPB;

    // ---- Stage: global -> LDS, lane-contiguous float4 (the R1 pattern that fetched 47 MB) ----
    if (n == CPB) {
        // 256 cells * 30 floats = 7680 floats = 1920 float4; block base (cell*120B) is 16B-aligned.
        const float4* gin = (const float4*)(in + (size_t)base * CC);
        const float4* gtg = (const float4*)(tg + (size_t)base * CC);
        float4* lin = (float4*)s_in;
        float4* ltg = (float4*)s_tg;
        #pragma unroll
        for (int k = 0; k < 8; ++k) {
            const int idx = tid + k * 256;
            if (idx < 1920) {
                lin[idx] = gin[idx];
                ltg[idx] = gtg[idx];
            }
        }
    } else {
        const int lim = n * CC;
        for (int k = tid; k < lim; k += 256) {
            s_in[k] = in[(size_t)base * CC + k];
            s_tg[k] = tg[(size_t)base * CC + k];
        }
    }
    __syncthreads();

    // ---- Per-cell compute (LDS stride 30 floats -> 2-way bank alias, free) ----
    float a_boxes = 0.0f, a_conf = 0.0f, a_class = 0.0f;
    if (tid < n) {
        const float* f = s_in + tid * CC;
        const float* t = s_tg + tid * CC;
        const float inv_gs = 0.14285714285714285f;   // 1/7 (abs err ~1e-7 vs 0.4 threshold)

        const float conf_t = t[4];
        const float coord  = (conf_t > 0.0f)  ? 1.0f : 0.0f;
        const float noobj  = (conf_t == 0.0f) ? 1.0f : 0.0f;

        // no-object confidence loss (both predicted boxes)
        const float d0 = f[4] - t[4];
        const float d1 = f[9] - t[9];
        const float l_noobj = noobj * (d0 * d0 + d1 * d1);

        // target box corners (box 0 of targets)
        const float bt0 = t[0], bt1 = t[1], bt2 = t[2], bt3 = t[3];
        const float ttx = bt0 * inv_gs, tty = bt1 * inv_gs;
        const float txmin = ttx - 0.5f * bt2, tymin = tty - 0.5f * bt3;
        const float txmax = ttx + 0.5f * bt2, tymax = tty + 0.5f * bt3;
        const float tarea = (txmax - txmin) * (tymax - tymin);

        // predicted boxes
        const float px0 = f[0], py0 = f[1], pw0 = f[2], ph0 = f[3], pc0 = f[4];
        const float px1 = f[5], py1 = f[6], pw1 = f[7], ph1 = f[8], pc1 = f[9];

        float iou0, iou1;
        {
            const float cx = px0 * inv_gs, cy = py0 * inv_gs;
            const float xmin = cx - 0.5f * pw0, ymin = cy - 0.5f * ph0;
            const float xmax = cx + 0.5f * pw0, ymax = cy + 0.5f * ph0;
            const float wx = fmaxf(fminf(xmax, txmax) - fmaxf(xmin, txmin), 0.0f);
            const float wy = fmaxf(fminf(ymax, tymax) - fmaxf(ymin, tymin), 0.0f);
            const float inter = wx * wy;
            const float parea = (xmax - xmin) * (ymax - ymin);
            iou0 = inter / (parea + tarea - inter);
        }
        {
            const float cx = px1 * inv_gs, cy = py1 * inv_gs;
            const float xmin = cx - 0.5f * pw1, ymin = cy - 0.5f * ph1;
            const float xmax = cx + 0.5f * pw1, ymax = cy + 0.5f * ph1;
            const float wx = fmaxf(fminf(xmax, txmax) - fmaxf(xmin, txmin), 0.0f);
            const float wy = fmaxf(fminf(ymax, tymax) - fmaxf(ymin, tymin), 0.0f);
            const float inter = wx * wy;
            const float parea = (xmax - xmin) * (ymax - ymin);
            iou1 = inter / (parea + tarea - inter);
        }
        // jnp.argmax picks first max on ties -> strict > for box 1
        const bool  sel1    = iou1 > iou0;
        const float max_iou = fmaxf(iou0, iou1);

        const float rp0 = sel1 ? px1 : px0;
        const float rp1 = sel1 ? py1 : py0;
        const float rp2 = sel1 ? pw1 : pw0;
        const float rp3 = sel1 ? ph1 : ph0;
        const float rp4 = sel1 ? pc1 : pc0;

        const float dx = rp0 - bt0, dy = rp1 - bt1;
        const float sw = sqrtf(rp2) - sqrtf(bt2);
        const float sh = sqrtf(rp3) - sqrtf(bt3);
        const float dob = rp4 - max_iou;
        const float l_box = dx * dx + dy * dy + sw * sw + sh * sh;
        const float l_obj = dob * dob;

        float l_cls = 0.0f;
        #pragma unroll
        for (int j = 10; j < 30; ++j) {
            const float d = f[j] - t[j];
            l_cls += d * d;
        }

        a_boxes = coord * l_box;
        a_conf  = coord * l_obj + 0.5f * l_noobj;
        a_class = coord * l_cls;
    }

    // ---- Reduce: wave-64 shuffle, cross-wave via LDS, non-atomic ws partial ----
    #pragma unroll
    for (int off = 32; off > 0; off >>= 1) {
        a_boxes += __shfl_down(a_boxes, off, 64);
        a_conf  += __shfl_down(a_conf,  off, 64);
        a_class += __shfl_down(a_class, off, 64);
    }
    const int wave = tid >> 6;
    if ((tid & 63) == 0) {
        s_red[wave][0] = a_boxes;
        s_red[wave][1] = a_conf;
        s_red[wave][2] = a_class;
    }
    __syncthreads();
    if (tid == 0) {
        const float b = s_red[0][0] + s_red[1][0] + s_red[2][0] + s_red[3][0];
        const float c = s_red[0][1] + s_red[1][1] + s_red[2][1] + s_red[3][1];
        const float k = s_red[0][2] + s_red[1][2] + s_red[2][2] + s_red[3][2];
        ws[blockIdx.x]               = b;
        ws[blockIdx.x + pstride]     = c;
        ws[blockIdx.x + 2 * pstride] = k;
    }
}

// ---------------- finalize: sum block partials, scale, write out ----------------
__global__ __launch_bounds__(256) void yolo_finalize(
        const float* __restrict__ ws, float* __restrict__ out,
        int nblocks, int pstride, float inv_bs) {
    float b = 0.0f, c = 0.0f, k = 0.0f;
    for (int i = threadIdx.x; i < nblocks; i += 256) {
        b += ws[i];
        c += ws[i + pstride];
        k += ws[i + 2 * pstride];
    }
    #pragma unroll
    for (int off = 32; off > 0; off >>= 1) {
        b += __shfl_down(b, off, 64);
        c += __shfl_down(c, off, 64);
        k += __shfl_down(k, off, 64);
    }
    __shared__ float s_red[4][3];
    const int wave = threadIdx.x >> 6;
    if ((threadIdx.x & 63) == 0) {
        s_red[wave][0] = b;
        s_red[wave][1] = c;
        s_red[wave][2] = k;
    }
    __syncthreads();
    if (threadIdx.x == 0) {
        const float tb = s_red[0][0] + s_red[1][0] + s_red[2][0] + s_red[3][0];
        const float tc = s_red[0][1] + s_red[1][1] + s_red[2][1] + s_red[3][1];
        const float tk = s_red[0][2] + s_red[1][2] + s_red[2][2] + s_red[3][2];
        out[0] = 0.5f * tb * inv_bs;   // LAMBDA_COORD*(xy+wh)/bs
        out[1] = tc * inv_bs;          // (obj + 0.5*noobj)/bs
        out[2] = tk * inv_bs;          // class/bs
    }
}

extern "C" void kernel_launch(void* const* d_in, const int* in_sizes, int n_in,
                              void* d_out, int out_size, void* d_ws, size_t ws_size,
                              hipStream_t stream) {
    const float* in = (const float*)d_in[0];
    const float* tg = (const float*)d_in[1];
    float* out = (float*)d_out;
    float* ws  = (float*)d_ws;

    const int ncells = in_sizes[0] / CC;          // B * 49
    const int B = ncells / (GS * GS);
    const float inv_bs = 1.0f / (float)B;

    const int nblocks = (ncells + CPB - 1) / CPB; // 1568 at B=8192
    const int pstride = nblocks;

    yolo_main<<<nblocks, 256, 0, stream>>>(in, tg, ws, ncells, pstride);
    yolo_finalize<<<1, 256, 0, stream>>>(ws, out, nblocks, pstride, inv_bs);
}

// Round 6
// 115.277 us; speedup vs baseline: 1.1970x; 1.0195x over previous
//
#include <hip/hip_runtime.h>

#define CC 30                    // 5*NB + NC
#define TPW 64                   // cells per wave-tile
#define WPB 4                    // waves per block
#define TILE_FLOATS (TPW * CC)   // 1920 floats = 7680 B per array
#define TILE_VEC4   (TILE_FLOATS / 4)   // 480

// ---------------- main: wave-private LDS tiles, ZERO block barriers ----------------
__global__ __launch_bounds__(256) void yolo_main(
        const float* __restrict__ in,
        const float* __restrict__ tg,
        float* __restrict__ ws,
        int ncells, int nwaves_total, int pstride) {
    __shared__ float s_in[WPB * TILE_FLOATS];   // 30720 B
    __shared__ float s_tg[WPB * TILE_FLOATS];   // 30720 B

    const int tid   = threadIdx.x;
    const int lane  = tid & 63;
    const int wave  = tid >> 6;
    const int gwave = blockIdx.x * WPB + wave;

    float* lin = s_in + wave * TILE_FLOATS;     // this wave's private slice
    float* ltg = s_tg + wave * TILE_FLOATS;

    const int ntiles = (ncells + TPW - 1) / TPW;
    const float inv_gs = 0.14285714285714285f;  // 1/7 (abs err ~1e-7 vs 0.4 threshold)

    float a_boxes = 0.0f, a_conf = 0.0f, a_class = 0.0f;

    for (int tile = gwave; tile < ntiles; tile += nwaves_total) {
        const int cbase = tile * TPW;
        int n = ncells - cbase;
        if (n > TPW) n = TPW;

        // ---- Stage this wave's tile: lane-contiguous float4 (tile base 16B-aligned) ----
        if (n == TPW) {
            const float4* gin = (const float4*)(in + (size_t)cbase * CC);
            const float4* gtg = (const float4*)(tg + (size_t)cbase * CC);
            float4* vin = (float4*)lin;
            float4* vtg = (float4*)ltg;
            float4 bi[8], bt[8];
            // phase 1: issue all 16 independent global loads
            #pragma unroll
            for (int k = 0; k < 8; ++k) {
                const int idx = k * 64 + lane;
                if (idx < TILE_VEC4) { bi[k] = gin[idx]; bt[k] = gtg[idx]; }
            }
            // phase 2: LDS writes
            #pragma unroll
            for (int k = 0; k < 8; ++k) {
                const int idx = k * 64 + lane;
                if (idx < TILE_VEC4) { vin[idx] = bi[k]; vtg[idx] = bt[k]; }
            }
        } else {
            const int lim = n * CC;
            for (int k = lane; k < lim; k += 64) {
                lin[k] = in[(size_t)cbase * CC + k];
                ltg[k] = tg[(size_t)cbase * CC + k];
            }
        }
        // In-wave ordering only: producer == consumer wave. DS ops from one wave
        // complete in order; the fence stops compiler reordering across it.
        asm volatile("s_waitcnt vmcnt(0) lgkmcnt(0)" ::: "memory");
        __builtin_amdgcn_wave_barrier();

        // ---- Per-cell compute: cell = lane (LDS stride 30; 4-way alias, minor) ----
        if (lane < n) {
            const float* f = lin + lane * CC;
            const float* t = ltg + lane * CC;

            const float conf_t = t[4];
            const float coord  = (conf_t > 0.0f)  ? 1.0f : 0.0f;
            const float noobj  = (conf_t == 0.0f) ? 1.0f : 0.0f;

            const float d0 = f[4] - t[4];
            const float d1 = f[9] - t[9];
            const float l_noobj = noobj * (d0 * d0 + d1 * d1);

            const float bt0 = t[0], bt1 = t[1], bt2 = t[2], bt3 = t[3];
            const float ttx = bt0 * inv_gs, tty = bt1 * inv_gs;
            const float txmin = ttx - 0.5f * bt2, tymin = tty - 0.5f * bt3;
            const float txmax = ttx + 0.5f * bt2, tymax = tty + 0.5f * bt3;
            const float tarea = (txmax - txmin) * (tymax - tymin);

            const float px0 = f[0], py0 = f[1], pw0 = f[2], ph0 = f[3], pc0 = f[4];
            const float px1 = f[5], py1 = f[6], pw1 = f[7], ph1 = f[8], pc1 = f[9];

            float iou0, iou1;
            {
                const float cx = px0 * inv_gs, cy = py0 * inv_gs;
                const float xmin = cx - 0.5f * pw0, ymin = cy - 0.5f * ph0;
                const float xmax = cx + 0.5f * pw0, ymax = cy + 0.5f * ph0;
                const float wx = fmaxf(fminf(xmax, txmax) - fmaxf(xmin, txmin), 0.0f);
                const float wy = fmaxf(fminf(ymax, tymax) - fmaxf(ymin, tymin), 0.0f);
                const float inter = wx * wy;
                const float parea = (xmax - xmin) * (ymax - ymin);
                iou0 = inter / (parea + tarea - inter);
            }
            {
                const float cx = px1 * inv_gs, cy = py1 * inv_gs;
                const float xmin = cx - 0.5f * pw1, ymin = cy - 0.5f * ph1;
                const float xmax = cx + 0.5f * pw1, ymax = cy + 0.5f * ph1;
                const float wx = fmaxf(fminf(xmax, txmax) - fmaxf(xmin, txmin), 0.0f);
                const float wy = fmaxf(fminf(ymax, tymax) - fmaxf(ymin, tymin), 0.0f);
                const float inter = wx * wy;
                const float parea = (xmax - xmin) * (ymax - ymin);
                iou1 = inter / (parea + tarea - inter);
            }
            // jnp.argmax picks first max on ties -> strict > for box 1
            const bool  sel1    = iou1 > iou0;
            const float max_iou = fmaxf(iou0, iou1);

            const float rp0 = sel1 ? px1 : px0;
            const float rp1 = sel1 ? py1 : py0;
            const float rp2 = sel1 ? pw1 : pw0;
            const float rp3 = sel1 ? ph1 : ph0;
            const float rp4 = sel1 ? pc1 : pc0;

            const float dx = rp0 - bt0, dy = rp1 - bt1;
            const float sw = sqrtf(rp2) - sqrtf(bt2);
            const float sh = sqrtf(rp3) - sqrtf(bt3);
            const float dob = rp4 - max_iou;
            const float l_box = dx * dx + dy * dy + sw * sw + sh * sh;
            const float l_obj = dob * dob;

            float l_cls = 0.0f;
            #pragma unroll
            for (int j = 10; j < 30; ++j) {
                const float d = f[j] - t[j];
                l_cls += d * d;
            }

            a_boxes += coord * l_box;
            a_conf  += coord * l_obj + 0.5f * l_noobj;
            a_class += coord * l_cls;
        }
        // keep next iteration's LDS writes behind this iteration's reads
        __builtin_amdgcn_wave_barrier();
    }

    // ---- wave-64 shuffle reduce; one partial triple per WAVE (no block reduce) ----
    #pragma unroll
    for (int off = 32; off > 0; off >>= 1) {
        a_boxes += __shfl_down(a_boxes, off, 64);
        a_conf  += __shfl_down(a_conf,  off, 64);
        a_class += __shfl_down(a_class, off, 64);
    }
    if (lane == 0) {
        ws[gwave]               = a_boxes;
        ws[gwave + pstride]     = a_conf;
        ws[gwave + 2 * pstride] = a_class;
    }
}

// ---------------- finalize: sum per-wave partials, scale, write out ----------------
__global__ __launch_bounds__(256) void yolo_finalize(
        const float* __restrict__ ws, float* __restrict__ out,
        int nparts, int pstride, float inv_bs) {
    float b = 0.0f, c = 0.0f, k = 0.0f;
    for (int i = threadIdx.x; i < nparts; i += 256) {
        b += ws[i];
        c += ws[i + pstride];
        k += ws[i + 2 * pstride];
    }
    #pragma unroll
    for (int off = 32; off > 0; off >>= 1) {
        b += __shfl_down(b, off, 64);
        c += __shfl_down(c, off, 64);
        k += __shfl_down(k, off, 64);
    }
    __shared__ float s_red[4][3];
    const int wave = threadIdx.x >> 6;
    if ((threadIdx.x & 63) == 0) {
        s_red[wave][0] = b;
        s_red[wave][1] = c;
        s_red[wave][2] = k;
    }
    __syncthreads();
    if (threadIdx.x == 0) {
        const float tb = s_red[0][0] + s_red[1][0] + s_red[2][0] + s_red[3][0];
        const float tc = s_red[0][1] + s_red[1][1] + s_red[2][1] + s_red[3][1];
        const float tk = s_red[0][2] + s_red[1][2] + s_red[2][2] + s_red[3][2];
        out[0] = 0.5f * tb * inv_bs;   // LAMBDA_COORD*(xy+wh)/bs
        out[1] = tc * inv_bs;          // (obj + 0.5*noobj)/bs
        out[2] = tk * inv_bs;          // class/bs
    }
}

extern "C" void kernel_launch(void* const* d_in, const int* in_sizes, int n_in,
                              void* d_out, int out_size, void* d_ws, size_t ws_size,
                              hipStream_t stream) {
    const float* in = (const float*)d_in[0];
    const float* tg = (const float*)d_in[1];
    float* out = (float*)d_out;
    float* ws  = (float*)d_ws;

    const int ncells = in_sizes[0] / CC;          // B * 49
    const int B = ncells / (49);
    const float inv_bs = 1.0f / (float)B;

    // persistent grid: 2 blocks/CU (LDS 61 KB) -> 512 blocks, 2048 waves
    const int nblocks = 512;
    const int nwaves  = nblocks * WPB;
    const int pstride = nwaves;

    yolo_main<<<nblocks, 256, 0, stream>>>(in, tg, ws, ncells, nwaves, pstride);
    yolo_finalize<<<1, 256, 0, stream>>>(ws, out, nwaves, pstride, inv_bs);
}